// Round 15
// baseline (406.764 us; speedup 1.0000x reference)
//
#include <hip/hip_runtime.h>
#include <math.h>

#define B_ 2
#define DMODEL 128
#define DIN 256
#define DSTATE 16
#define DTR 8
#define OUTC 128
#define Lseq 4096
#define NC 256          // chunks per batch
#define LC 16           // timesteps per chunk
#define NBLK 512        // grid size (must equal launch grid; 2 blocks/CU, all co-resident)

__device__ __forceinline__ float siluf(float x){ return x / (1.f + __expf(-x)); }

// dA[s] = e1^(s+1), s=0..15, via log-depth power ladder (15 muls, depth ~4).
__device__ __forceinline__ void build_dA(float e1, float* dAv){
    float e2 = e1*e1, e4 = e2*e2, e8 = e4*e4;
    dAv[0]=e1;         dAv[1]=e2;         dAv[2]=e2*e1;       dAv[3]=e4;
    dAv[4]=e4*e1;      dAv[5]=e4*e2;      dAv[6]=e4*dAv[2];   dAv[7]=e8;
    dAv[8]=e8*e1;      dAv[9]=e8*e2;      dAv[10]=e8*dAv[2];  dAv[11]=e8*e4;
    dAv[12]=e8*dAv[4]; dAv[13]=e8*dAv[5]; dAv[14]=e8*dAv[6];  dAv[15]=e8*e8;
}

__device__ __forceinline__ float softplusf(float a){
    return (a > 20.f) ? a : __logf(1.f + __expf(a));
}

// Manual grid barrier: device-scope atomics + explicit fences. Safe under graph capture
// (plain launch), safe across XCDs (threadfence = agent-scope release/acquire -> L2 wb/inv).
// Counter is memset to 0 before each launch; barrier k waits for batch (k+1)*NBLK.
__device__ __forceinline__ void gridbar(unsigned* cnt, int t){
    __syncthreads();                       // all block stores issued & complete
    if (t == 0){
        __threadfence();                   // release: write back this XCD's dirty L2
        unsigned ticket = atomicAdd(cnt, 1u);
        unsigned target = ((ticket >> 9) + 1u) << 9;    // next multiple of 512
        while (atomicAdd(cnt, 0u) < target){ __builtin_amdgcn_s_sleep(8); }
        __threadfence();                   // acquire: invalidate stale cached lines
    }
    __syncthreads();                       // rest of block waits for t0
}

// =========================================================================================
// FUSED kernel (plain launch + manual grid barrier): 512 blocks x 256 threads, 2/CU resident.
//   Phase 1 (block = chunk): in_proj GEMM + conv + x_proj + dt_proj + scan pass 1 -> PSw.
//   gridbar()
//   Phase 2 (block = r-group): hierarchical chunk combine PSw -> Iw (entry states).
//   gridbar()
//   Phase 3 (same block = same chunk): scan pass 3 from hot LDS/registers + out_proj + LN + store.
// Eliminates zs/xc/dt/Bm/Cm round-trips (48+ MB) and two kernel launches.
// __launch_bounds__(256,2): pins VGPR <= 256 so 2 blocks/CU co-residency is GUARANTEED
// (deadlock-free barrier requires all 512 resident: LDS 60KB*2<=160KB, waves 8<=32). [audited]
// =========================================================================================
__global__ __launch_bounds__(256, 2) void k_fused(const float* __restrict__ x1,
        const float* __restrict__ Win,
        const float* __restrict__ convw, const float* __restrict__ convb,
        const float* __restrict__ Wx, const float* __restrict__ Wdt,
        const float* __restrict__ bdt, const float* __restrict__ Alog,
        const float* __restrict__ Dv, const float* __restrict__ Wout,
        const float* __restrict__ lng, const float* __restrict__ lnb,
        float2* __restrict__ PSw, float* __restrict__ Iw, unsigned* __restrict__ bar,
        float* __restrict__ out){
    // sbuf union across phases (all reuses separated by barriers):
    //   phase 0-1: xt[128*20] (2560)   phase 2.5-3(x_proj): Wxs[256*40] (10240)
    //   phase 2:   gps (512) + ge (256)
    //   phase 3:   ysm[256*18] (4608) + os[128*18] (2304)
    __shared__ float sbuf[10240];
    __shared__ float xcs[16*257];      // conv output [l][d] — live phase 1 -> phase 3
    __shared__ float xdbl[16*40];      // x_proj output [l][40] — live phase 1 -> phase 3

    int blk = blockIdx.x;              // 512 = b x 256 chunks
    int b  = blk >> 8;
    int cb = blk & 255;
    int l0 = cb << 4;
    int t  = threadIdx.x;

    // ==================== PHASE 1 ====================
    float* xt  = sbuf;                 // [c][p] stride 20 (80B rows, 16B-aligned)
    float* Wxs = sbuf;
    const float* xb = x1 + (size_t)b * DMODEL * Lseq;
    for (int e = t; e < 128*19; e += 256){
        int c = e / 19, p = e - c*19;
        int l = l0 - 3 + p;
        xt[c*20 + p] = (l >= 0) ? xb[(size_t)c*Lseq + l] : 0.f;
    }
    __syncthreads();

    // ---- in_proj GEMM. thread t -> xin col t (19 p incl halo) + z col t (16 p) ----
    float acc0[19], acc1[16];
    #pragma unroll
    for (int p=0;p<19;++p){acc0[p]=0.f;}
    #pragma unroll
    for (int p=0;p<16;++p){acc1[p]=0.f;}
    #pragma unroll 4
    for (int k=0;k<DMODEL;++k){
        float w0 = Win[k*512 + t];
        float w1 = Win[k*512 + t + 256];
        const float4* xp = (const float4*)&xt[k*20];
        float4 v0 = xp[0], v1 = xp[1], v2 = xp[2], v3 = xp[3], v4 = xp[4];
        float xv[19] = { v0.x,v0.y,v0.z,v0.w, v1.x,v1.y,v1.z,v1.w,
                         v2.x,v2.y,v2.z,v2.w, v3.x,v3.y,v3.z,v3.w,
                         v4.x,v4.y,v4.z };
        #pragma unroll
        for (int p=0;p<19;++p) acc0[p] = fmaf(xv[p], w0, acc0[p]);
        #pragma unroll
        for (int p=0;p<16;++p) acc1[p] = fmaf(xv[p+3], w1, acc1[p]);
    }
    // z gate: keep in REGISTERS
    float zvv[16];
    #pragma unroll
    for (int p=0;p<16;++p) zvv[p] = siluf(acc1[p]);

    // ---- causal depthwise conv + silu from registers -> xcs (LDS only) ----
    {
        float cw0 = convw[t*4+0], cw1 = convw[t*4+1], cw2 = convw[t*4+2], cw3 = convw[t*4+3];
        float bb = convb[t];
        #pragma unroll
        for (int l = 0; l < 16; ++l){
            float acc = bb;
            acc = fmaf(acc0[l],   cw0, acc);
            acc = fmaf(acc0[l+1], cw1, acc);
            acc = fmaf(acc0[l+2], cw2, acc);
            acc = fmaf(acc0[l+3], cw3, acc);
            xcs[l*257 + t] = siluf(acc);
        }
    }
    __syncthreads();                   // all waves done reading xt

    // ---- stage Wx into LDS (coalesced float4) ----
    {
        const float4* Wg = (const float4*)Wx;
        float4* Ws = (float4*)Wxs;
        #pragma unroll
        for (int e = t; e < 2560; e += 256)
            Ws[e] = Wg[e];
    }
    __syncthreads();

    // ---- x_proj from LDS (128 active threads: 16 rows x 8 col-groups of 5) ----
    if (t < 128){
        int jg = t & 7;
        int lg = t >> 3;
        int j0 = jg * 5;
        float a0=0.f, a1=0.f, a2=0.f, a3=0.f, a4=0.f;
        const float* xrow = xcs + lg*257;
        const float* wbase = Wxs + j0;
        #pragma unroll 8
        for (int d = 0; d < 256; ++d){
            float xv = xrow[d];
            const float* wr = wbase + d*40;
            a0 = fmaf(xv, wr[0], a0);
            a1 = fmaf(xv, wr[1], a1);
            a2 = fmaf(xv, wr[2], a2);
            a3 = fmaf(xv, wr[3], a3);
            a4 = fmaf(xv, wr[4], a4);
        }
        float* xo = xdbl + lg*40 + j0;
        xo[0]=a0; xo[1]=a1; xo[2]=a2; xo[3]=a3; xo[4]=a4;
    }
    __syncthreads();

    // ---- dt_proj + softplus + fused scan pass 1; dtv in registers; ONLY PSw stored ----
    float Av[16], dtv[16];
    bool fastA = true;
    {
        float wd[DTR];
        #pragma unroll
        for (int r=0;r<DTR;++r) wd[r] = Wdt[r*DIN + t];
        float bv = bdt[t];
        {
            const float4* Ap = (const float4*)(Alog + t*DSTATE);
            #pragma unroll
            for (int q=0;q<4;++q){
                float4 a = Ap[q];
                Av[q*4]   = -__expf(a.x);
                Av[q*4+1] = -__expf(a.y);
                Av[q*4+2] = -__expf(a.z);
                Av[q*4+3] = -__expf(a.w);
            }
        }
        #pragma unroll
        for (int i=1;i<16;++i)
            fastA = fastA && (fabsf(Av[i] - (float)(i+1)*Av[0]) <= 1e-6f*fabsf(Av[i]));
        float P[16], S[16];
        #pragma unroll
        for (int s=0;s<16;++s){ P[s]=1.f; S[s]=0.f; }
        #pragma unroll
        for (int l=0;l<16;++l){
            float a = bv;
            #pragma unroll
            for (int r=0;r<DTR;++r) a = fmaf(xdbl[l*40 + r], wd[r], a);
            float dtvl = softplusf(a);
            dtv[l] = dtvl;
            float xcv = xcs[l*257 + t];
            float dx  = dtvl*xcv;
            const float4* Bv = (const float4*)&xdbl[l*40 + DTR];
            float4 B0 = Bv[0], B1 = Bv[1], B2 = Bv[2], B3 = Bv[3];
            float dAv[16];
            if (fastA){
                build_dA(__expf(dtvl*Av[0]), dAv);
            } else {
                #pragma unroll
                for (int i=0;i<16;++i) dAv[i] = __expf(dtvl*Av[i]);
            }
            #define ST1(i, bval) { P[i] *= dAv[i]; S[i] = fmaf(dAv[i], S[i], dx*(bval)); }
            ST1(0,B0.x) ST1(1,B0.y) ST1(2,B0.z) ST1(3,B0.w)
            ST1(4,B1.x) ST1(5,B1.y) ST1(6,B1.z) ST1(7,B1.w)
            ST1(8,B2.x) ST1(9,B2.y) ST1(10,B2.z) ST1(11,B2.w)
            ST1(12,B3.x) ST1(13,B3.y) ST1(14,B3.z) ST1(15,B3.w)
            #undef ST1
        }
        // PSw per-chunk layout [s][d]: coalesced 512B stores
        float2* ps2 = PSw + ((size_t)(b*NC + cb))*4096;
        #pragma unroll
        for (int s=0;s<16;++s) ps2[s*256 + t] = make_float2(P[s], S[s]);
    }

    gridbar(bar, t);   // ================= all PSw globally visible =================

    // ==================== PHASE 2: chunk combine (block = r-group of 16) ====================
    {
        float2* gps = (float2*)sbuf;       // [16][16] float2
        float*  ge  = sbuf + 512;          // [16][16] float
        int r0 = (blk & 255) * 16;
        int rr = t & 15;
        int cg2 = t >> 4;                  // chunk-group 0..15 (16 chunks each)
        size_t base = ((size_t)(b*NC + cg2*16))*4096 + r0 + rr;
        float Pl[16], Sl[16];
        float Pa = 1.f, Sa = 0.f;
        #pragma unroll
        for (int i=0;i<16;++i){
            float2 ps = PSw[base + (size_t)i*4096];
            Pl[i] = ps.x; Sl[i] = ps.y;
            Pa = ps.x * Pa;
            Sa = fmaf(ps.x, Sa, ps.y);
        }
        gps[cg2*16 + rr] = make_float2(Pa, Sa);
        __syncthreads();
        if (t < 16){
            float H = 0.f;
            #pragma unroll
            for (int g=0; g<16; ++g){
                float2 ps = gps[g*16 + t];
                ge[g*16 + t] = H;
                H = fmaf(ps.x, H, ps.y);
            }
        }
        __syncthreads();
        float H = ge[cg2*16 + rr];
        #pragma unroll
        for (int i=0;i<16;++i){
            Iw[base + (size_t)i*4096] = H;
            H = fmaf(Pl[i], H, Sl[i]);
        }
    }

    gridbar(bar, t);   // ================= all Iw globally visible =================

    // ==================== PHASE 3: scan pass 3 + out_proj + LN + store ====================
    float* ysm = sbuf;          // [256*18]
    float* os  = sbuf + 4608;   // [128*18]
    float h[16];
    {   // entry states: Iw per-chunk layout [s][d] -> 16 coalesced b32 loads
        const float* Ip = Iw + ((size_t)(b*NC + cb))*4096 + t;
        #pragma unroll
        for (int s=0;s<16;++s) h[s] = Ip[s*256];
    }
    float Dd = Dv[t];
    #pragma unroll
    for (int l=0;l<LC;++l){
        float dtl = dtv[l];
        float xcv = xcs[l*257 + t];
        float dx  = dtl*xcv;
        const float4* Bv = (const float4*)&xdbl[l*40 + DTR];
        float4 B0 = Bv[0], B1 = Bv[1], B2 = Bv[2], B3 = Bv[3];
        const float4* Cv = (const float4*)&xdbl[l*40 + DTR + DSTATE];
        float4 C0 = Cv[0], C1 = Cv[1], C2 = Cv[2], C3 = Cv[3];
        float dAv[16];
        if (fastA){
            build_dA(__expf(dtl*Av[0]), dAv);
        } else {
            #pragma unroll
            for (int i=0;i<16;++i) dAv[i] = __expf(dtl*Av[i]);
        }
        float y = 0.f;
        #define ST3(i, bval, cval) { h[i] = fmaf(dAv[i], h[i], dx*(bval)); y = fmaf(h[i], (cval), y); }
        ST3(0,B0.x,C0.x) ST3(1,B0.y,C0.y) ST3(2,B0.z,C0.z) ST3(3,B0.w,C0.w)
        ST3(4,B1.x,C1.x) ST3(5,B1.y,C1.y) ST3(6,B1.z,C1.z) ST3(7,B1.w,C1.w)
        ST3(8,B2.x,C2.x) ST3(9,B2.y,C2.y) ST3(10,B2.z,C2.z) ST3(11,B2.w,C2.w)
        ST3(12,B3.x,C3.x) ST3(13,B3.y,C3.y) ST3(14,B3.z,C3.z) ST3(15,B3.w,C3.w)
        #undef ST3
        ysm[t*18 + l] = (y + Dd*xcv)*zvv[l];
    }
    __syncthreads();
    // ---- out_proj: 16l x 128c tile. lg=t>>5 -> l {lg*2, lg*2+1}; cg=t&31 -> 4 c.
    {
        int lg = t >> 5, cgc = t & 31;
        int l0t = lg*2, c0 = cgc*4;
        float acc[2][4];
        #pragma unroll
        for (int i=0;i<2;++i)
            #pragma unroll
            for (int j=0;j<4;++j) acc[i][j]=0.f;
        #pragma unroll 4
        for (int k=0;k<DIN;++k){
            float2 yv = *(const float2*)&ysm[k*18 + l0t];
            float4 wv = *(const float4*)&Wout[k*OUTC + c0];
            acc[0][0]=fmaf(yv.x,wv.x,acc[0][0]); acc[0][1]=fmaf(yv.x,wv.y,acc[0][1]);
            acc[0][2]=fmaf(yv.x,wv.z,acc[0][2]); acc[0][3]=fmaf(yv.x,wv.w,acc[0][3]);
            acc[1][0]=fmaf(yv.y,wv.x,acc[1][0]); acc[1][1]=fmaf(yv.y,wv.y,acc[1][1]);
            acc[1][2]=fmaf(yv.y,wv.z,acc[1][2]); acc[1][3]=fmaf(yv.y,wv.w,acc[1][3]);
        }
        float4 gm = *(const float4*)&lng[c0];
        float4 bt = *(const float4*)&lnb[c0];
        #pragma unroll
        for (int i=0;i<2;++i){
            float rs = acc[i][0]+acc[i][1]+acc[i][2]+acc[i][3];
            #pragma unroll
            for (int m=16;m>0;m>>=1) rs += __shfl_xor(rs, m, 64);
            float mu = rs * (1.f/128.f);
            float d0 = acc[i][0]-mu, d1 = acc[i][1]-mu, d2 = acc[i][2]-mu, d3 = acc[i][3]-mu;
            float sq = d0*d0+d1*d1+d2*d2+d3*d3;
            #pragma unroll
            for (int m=16;m>0;m>>=1) sq += __shfl_xor(sq, m, 64);
            float rstd = rsqrtf(sq * (1.f/128.f) + 1e-5f);
            int lidx = l0t + i;
            os[(c0+0)*18 + lidx] = d0*rstd*gm.x + bt.x;
            os[(c0+1)*18 + lidx] = d1*rstd*gm.y + bt.y;
            os[(c0+2)*18 + lidx] = d2*rstd*gm.z + bt.z;
            os[(c0+3)*18 + lidx] = d3*rstd*gm.w + bt.w;
        }
    }
    __syncthreads();
    // store: cc = t>>1 (0..127), sel = t&1 -> 8 consecutive l = 32B per lane
    {
        int cc = t >> 1, sel = t & 1;
        const float* ip = &os[cc*18 + sel*8];
        float2 a0 = *(const float2*)(ip);
        float2 a1 = *(const float2*)(ip+2);
        float2 a2 = *(const float2*)(ip+4);
        float2 a3 = *(const float2*)(ip+6);
        float* op = out + ((size_t)(b*OUTC + cc))*Lseq + l0 + sel*8;
        *(float4*)(op)   = make_float4(a0.x,a0.y,a1.x,a1.y);
        *(float4*)(op+4) = make_float4(a2.x,a2.y,a3.x,a3.y);
    }
}

extern "C" void kernel_launch(void* const* d_in, const int* in_sizes, int n_in,
                              void* d_out, int out_size, void* d_ws, size_t ws_size,
                              hipStream_t stream) {
    const float* x1    = (const float*)d_in[0];
    const float* Win   = (const float*)d_in[1];
    const float* convw = (const float*)d_in[2];
    const float* convb = (const float*)d_in[3];
    const float* Wx    = (const float*)d_in[4];
    const float* Wdt   = (const float*)d_in[5];
    const float* bdt   = (const float*)d_in[6];
    const float* Alog  = (const float*)d_in[7];
    const float* Dv    = (const float*)d_in[8];
    const float* Wout  = (const float*)d_in[9];
    const float* lng   = (const float*)d_in[10];
    const float* lnb   = (const float*)d_in[11];
    float* out = (float*)d_out;

    float2*   PSw = (float2*)d_ws;                 // 2,097,152 float2 = 16 MB
    float*    Iw  = (float*)(PSw + 2097152);       // 2,097,152 float  =  8 MB
    unsigned* bar = (unsigned*)(Iw + 2097152);     // barrier counter (8 B)

    hipMemsetAsync(bar, 0, 8, stream);             // reset barrier each replay
    k_fused<<<512, 256, 0, stream>>>(x1, Win, convw, convb, Wx, Wdt, bdt, Alog,
                                     Dv, Wout, lng, lnb, PSw, Iw, bar, out);
}

// Round 18
// 399.111 us; speedup vs baseline: 1.0192x; 1.0192x over previous
//
#include <hip/hip_runtime.h>
#include <math.h>

#define B_ 2
#define DMODEL 128
#define DIN 256
#define DSTATE 16
#define DTR 8
#define OUTC 128
#define Lseq 4096
#define NC 256          // chunks per batch
#define LC 16           // timesteps per chunk
#define NBLK 512        // grid size (must equal launch grid; 2 blocks/CU, all co-resident)

__device__ __forceinline__ float siluf(float x){ return x / (1.f + __expf(-x)); }

// dA[s] = e1^(s+1), s=0..15, via log-depth power ladder (15 muls, depth ~4).
__device__ __forceinline__ void build_dA(float e1, float* dAv){
    float e2 = e1*e1, e4 = e2*e2, e8 = e4*e4;
    dAv[0]=e1;         dAv[1]=e2;         dAv[2]=e2*e1;       dAv[3]=e4;
    dAv[4]=e4*e1;      dAv[5]=e4*e2;      dAv[6]=e4*dAv[2];   dAv[7]=e8;
    dAv[8]=e8*e1;      dAv[9]=e8*e2;      dAv[10]=e8*dAv[2];  dAv[11]=e8*e4;
    dAv[12]=e8*dAv[4]; dAv[13]=e8*dAv[5]; dAv[14]=e8*dAv[6];  dAv[15]=e8*e8;
}

__device__ __forceinline__ float softplusf(float a){
    return (a > 20.f) ? a : __logf(1.f + __expf(a));
}

// Manual grid barrier v2 — R15 post-mortem fix: POLL WITH ATOMIC LOAD, NOT RMW.
// R15's atomicAdd(cnt,0) polling = 5.8M serialized RMWs (372 MB writes, ~130 us/barrier).
// Agent-scope atomic load reads at the coherence point WITHOUT exclusive ownership:
// concurrent readers share the line, zero write traffic. Arrival stays 1 RMW per block.
__device__ __forceinline__ void gridbar(unsigned* cnt, int t){
    __syncthreads();                       // all block stores issued & complete
    if (t == 0){
        __threadfence();                   // release: write back this XCD's dirty L2
        unsigned ticket = atomicAdd(cnt, 1u);
        unsigned target = ((ticket >> 9) + 1u) << 9;    // next multiple of 512
        while (__hip_atomic_load(cnt, __ATOMIC_RELAXED, __HIP_MEMORY_SCOPE_AGENT) < target){
            __builtin_amdgcn_s_sleep(32);  // ~0.85 us backoff between polls
        }
        __threadfence();                   // acquire: discard stale cached lines
    }
    __syncthreads();                       // rest of block waits for t0
}

// =========================================================================================
// FUSED kernel (plain launch + manual grid barrier): 512 blocks x 256 threads, 2/CU resident.
//   Phase 1 (block = chunk): in_proj GEMM + conv + x_proj + dt_proj + scan pass 1 -> PSw.
//   gridbar()
//   Phase 2 (block = r-group): hierarchical chunk combine PSw -> Iw (entry states).
//   gridbar()
//   Phase 3 (same block = same chunk): scan pass 3 from hot LDS/registers + out_proj + LN + store.
// Correctness of this fused dataflow + fence scheme was VERIFIED in R15 (absmax 4.88e-4).
// __launch_bounds__(256,2): pins VGPR <= 256 so 2 blocks/CU co-residency is GUARANTEED
// (deadlock-free barrier requires all 512 resident: LDS 60KB*2<=160KB, waves 8<=32). [audited]
// =========================================================================================
__global__ __launch_bounds__(256, 2) void k_fused(const float* __restrict__ x1,
        const float* __restrict__ Win,
        const float* __restrict__ convw, const float* __restrict__ convb,
        const float* __restrict__ Wx, const float* __restrict__ Wdt,
        const float* __restrict__ bdt, const float* __restrict__ Alog,
        const float* __restrict__ Dv, const float* __restrict__ Wout,
        const float* __restrict__ lng, const float* __restrict__ lnb,
        float2* __restrict__ PSw, float* __restrict__ Iw, unsigned* __restrict__ bar,
        float* __restrict__ out){
    // sbuf union across phases (all reuses separated by barriers):
    //   phase 0-1: xt[128*20] (2560)   phase 2.5-3(x_proj): Wxs[256*40] (10240)
    //   phase 2:   gps (512) + ge (256)
    //   phase 3:   ysm[256*18] (4608) + os[128*18] (2304)
    __shared__ float sbuf[10240];
    __shared__ float xcs[16*257];      // conv output [l][d] — live phase 1 -> phase 3
    __shared__ float xdbl[16*40];      // x_proj output [l][40] — live phase 1 -> phase 3

    int blk = blockIdx.x;              // 512 = b x 256 chunks
    int b  = blk >> 8;
    int cb = blk & 255;
    int l0 = cb << 4;
    int t  = threadIdx.x;

    // ==================== PHASE 1 ====================
    float* xt  = sbuf;                 // [c][p] stride 20 (80B rows, 16B-aligned)
    float* Wxs = sbuf;
    const float* xb = x1 + (size_t)b * DMODEL * Lseq;
    for (int e = t; e < 128*19; e += 256){
        int c = e / 19, p = e - c*19;
        int l = l0 - 3 + p;
        xt[c*20 + p] = (l >= 0) ? xb[(size_t)c*Lseq + l] : 0.f;
    }
    __syncthreads();

    // ---- in_proj GEMM. thread t -> xin col t (19 p incl halo) + z col t (16 p) ----
    float acc0[19], acc1[16];
    #pragma unroll
    for (int p=0;p<19;++p){acc0[p]=0.f;}
    #pragma unroll
    for (int p=0;p<16;++p){acc1[p]=0.f;}
    #pragma unroll 4
    for (int k=0;k<DMODEL;++k){
        float w0 = Win[k*512 + t];
        float w1 = Win[k*512 + t + 256];
        const float4* xp = (const float4*)&xt[k*20];
        float4 v0 = xp[0], v1 = xp[1], v2 = xp[2], v3 = xp[3], v4 = xp[4];
        float xv[19] = { v0.x,v0.y,v0.z,v0.w, v1.x,v1.y,v1.z,v1.w,
                         v2.x,v2.y,v2.z,v2.w, v3.x,v3.y,v3.z,v3.w,
                         v4.x,v4.y,v4.z };
        #pragma unroll
        for (int p=0;p<19;++p) acc0[p] = fmaf(xv[p], w0, acc0[p]);
        #pragma unroll
        for (int p=0;p<16;++p) acc1[p] = fmaf(xv[p+3], w1, acc1[p]);
    }
    // z gate: keep in REGISTERS
    float zvv[16];
    #pragma unroll
    for (int p=0;p<16;++p) zvv[p] = siluf(acc1[p]);

    // ---- causal depthwise conv + silu from registers -> xcs (LDS only) ----
    {
        float cw0 = convw[t*4+0], cw1 = convw[t*4+1], cw2 = convw[t*4+2], cw3 = convw[t*4+3];
        float bb = convb[t];
        #pragma unroll
        for (int l = 0; l < 16; ++l){
            float acc = bb;
            acc = fmaf(acc0[l],   cw0, acc);
            acc = fmaf(acc0[l+1], cw1, acc);
            acc = fmaf(acc0[l+2], cw2, acc);
            acc = fmaf(acc0[l+3], cw3, acc);
            xcs[l*257 + t] = siluf(acc);
        }
    }
    __syncthreads();                   // all waves done reading xt

    // ---- stage Wx into LDS (coalesced float4) ----
    {
        const float4* Wg = (const float4*)Wx;
        float4* Ws = (float4*)Wxs;
        #pragma unroll
        for (int e = t; e < 2560; e += 256)
            Ws[e] = Wg[e];
    }
    __syncthreads();

    // ---- x_proj from LDS (128 active threads: 16 rows x 8 col-groups of 5) ----
    if (t < 128){
        int jg = t & 7;
        int lg = t >> 3;
        int j0 = jg * 5;
        float a0=0.f, a1=0.f, a2=0.f, a3=0.f, a4=0.f;
        const float* xrow = xcs + lg*257;
        const float* wbase = Wxs + j0;
        #pragma unroll 8
        for (int d = 0; d < 256; ++d){
            float xv = xrow[d];
            const float* wr = wbase + d*40;
            a0 = fmaf(xv, wr[0], a0);
            a1 = fmaf(xv, wr[1], a1);
            a2 = fmaf(xv, wr[2], a2);
            a3 = fmaf(xv, wr[3], a3);
            a4 = fmaf(xv, wr[4], a4);
        }
        float* xo = xdbl + lg*40 + j0;
        xo[0]=a0; xo[1]=a1; xo[2]=a2; xo[3]=a3; xo[4]=a4;
    }
    __syncthreads();

    // ---- dt_proj + softplus + fused scan pass 1; dtv in registers; ONLY PSw stored ----
    float Av[16], dtv[16];
    bool fastA = true;
    {
        float wd[DTR];
        #pragma unroll
        for (int r=0;r<DTR;++r) wd[r] = Wdt[r*DIN + t];
        float bv = bdt[t];
        {
            const float4* Ap = (const float4*)(Alog + t*DSTATE);
            #pragma unroll
            for (int q=0;q<4;++q){
                float4 a = Ap[q];
                Av[q*4]   = -__expf(a.x);
                Av[q*4+1] = -__expf(a.y);
                Av[q*4+2] = -__expf(a.z);
                Av[q*4+3] = -__expf(a.w);
            }
        }
        #pragma unroll
        for (int i=1;i<16;++i)
            fastA = fastA && (fabsf(Av[i] - (float)(i+1)*Av[0]) <= 1e-6f*fabsf(Av[i]));
        float P[16], S[16];
        #pragma unroll
        for (int s=0;s<16;++s){ P[s]=1.f; S[s]=0.f; }
        #pragma unroll
        for (int l=0;l<16;++l){
            float a = bv;
            #pragma unroll
            for (int r=0;r<DTR;++r) a = fmaf(xdbl[l*40 + r], wd[r], a);
            float dtvl = softplusf(a);
            dtv[l] = dtvl;
            float xcv = xcs[l*257 + t];
            float dx  = dtvl*xcv;
            const float4* Bv = (const float4*)&xdbl[l*40 + DTR];
            float4 B0 = Bv[0], B1 = Bv[1], B2 = Bv[2], B3 = Bv[3];
            float dAv[16];
            if (fastA){
                build_dA(__expf(dtvl*Av[0]), dAv);
            } else {
                #pragma unroll
                for (int i=0;i<16;++i) dAv[i] = __expf(dtvl*Av[i]);
            }
            #define ST1(i, bval) { P[i] *= dAv[i]; S[i] = fmaf(dAv[i], S[i], dx*(bval)); }
            ST1(0,B0.x) ST1(1,B0.y) ST1(2,B0.z) ST1(3,B0.w)
            ST1(4,B1.x) ST1(5,B1.y) ST1(6,B1.z) ST1(7,B1.w)
            ST1(8,B2.x) ST1(9,B2.y) ST1(10,B2.z) ST1(11,B2.w)
            ST1(12,B3.x) ST1(13,B3.y) ST1(14,B3.z) ST1(15,B3.w)
            #undef ST1
        }
        // PSw per-chunk layout [s][d]: coalesced 512B stores
        float2* ps2 = PSw + ((size_t)(b*NC + cb))*4096;
        #pragma unroll
        for (int s=0;s<16;++s) ps2[s*256 + t] = make_float2(P[s], S[s]);
    }

    gridbar(bar, t);   // ================= all PSw globally visible =================

    // ==================== PHASE 2: chunk combine (block = r-group of 16) ====================
    {
        float2* gps = (float2*)sbuf;       // [16][16] float2
        float*  ge  = sbuf + 512;          // [16][16] float
        int r0 = (blk & 255) * 16;
        int rr = t & 15;
        int cg2 = t >> 4;                  // chunk-group 0..15 (16 chunks each)
        size_t base = ((size_t)(b*NC + cg2*16))*4096 + r0 + rr;
        float Pl[16], Sl[16];
        float Pa = 1.f, Sa = 0.f;
        #pragma unroll
        for (int i=0;i<16;++i){
            float2 ps = PSw[base + (size_t)i*4096];
            Pl[i] = ps.x; Sl[i] = ps.y;
            Pa = ps.x * Pa;
            Sa = fmaf(ps.x, Sa, ps.y);
        }
        gps[cg2*16 + rr] = make_float2(Pa, Sa);
        __syncthreads();
        if (t < 16){
            float H = 0.f;
            #pragma unroll
            for (int g=0; g<16; ++g){
                float2 ps = gps[g*16 + t];
                ge[g*16 + t] = H;
                H = fmaf(ps.x, H, ps.y);
            }
        }
        __syncthreads();
        float H = ge[cg2*16 + rr];
        #pragma unroll
        for (int i=0;i<16;++i){
            Iw[base + (size_t)i*4096] = H;
            H = fmaf(Pl[i], H, Sl[i]);
        }
    }

    gridbar(bar, t);   // ================= all Iw globally visible =================

    // ==================== PHASE 3: scan pass 3 + out_proj + LN + store ====================
    float* ysm = sbuf;          // [256*18]
    float* os  = sbuf + 4608;   // [128*18]
    float h[16];
    {   // entry states: Iw per-chunk layout [s][d] -> 16 coalesced b32 loads
        const float* Ip = Iw + ((size_t)(b*NC + cb))*4096 + t;
        #pragma unroll
        for (int s=0;s<16;++s) h[s] = Ip[s*256];
    }
    float Dd = Dv[t];
    #pragma unroll
    for (int l=0;l<LC;++l){
        float dtl = dtv[l];
        float xcv = xcs[l*257 + t];
        float dx  = dtl*xcv;
        const float4* Bv = (const float4*)&xdbl[l*40 + DTR];
        float4 B0 = Bv[0], B1 = Bv[1], B2 = Bv[2], B3 = Bv[3];
        const float4* Cv = (const float4*)&xdbl[l*40 + DTR + DSTATE];
        float4 C0 = Cv[0], C1 = Cv[1], C2 = Cv[2], C3 = Cv[3];
        float dAv[16];
        if (fastA){
            build_dA(__expf(dtl*Av[0]), dAv);
        } else {
            #pragma unroll
            for (int i=0;i<16;++i) dAv[i] = __expf(dtl*Av[i]);
        }
        float y = 0.f;
        #define ST3(i, bval, cval) { h[i] = fmaf(dAv[i], h[i], dx*(bval)); y = fmaf(h[i], (cval), y); }
        ST3(0,B0.x,C0.x) ST3(1,B0.y,C0.y) ST3(2,B0.z,C0.z) ST3(3,B0.w,C0.w)
        ST3(4,B1.x,C1.x) ST3(5,B1.y,C1.y) ST3(6,B1.z,C1.z) ST3(7,B1.w,C1.w)
        ST3(8,B2.x,C2.x) ST3(9,B2.y,C2.y) ST3(10,B2.z,C2.z) ST3(11,B2.w,C2.w)
        ST3(12,B3.x,C3.x) ST3(13,B3.y,C3.y) ST3(14,B3.z,C3.z) ST3(15,B3.w,C3.w)
        #undef ST3
        ysm[t*18 + l] = (y + Dd*xcv)*zvv[l];
    }
    __syncthreads();
    // ---- out_proj: 16l x 128c tile. lg=t>>5 -> l {lg*2, lg*2+1}; cg=t&31 -> 4 c.
    {
        int lg = t >> 5, cgc = t & 31;
        int l0t = lg*2, c0 = cgc*4;
        float acc[2][4];
        #pragma unroll
        for (int i=0;i<2;++i)
            #pragma unroll
            for (int j=0;j<4;++j) acc[i][j]=0.f;
        #pragma unroll 4
        for (int k=0;k<DIN;++k){
            float2 yv = *(const float2*)&ysm[k*18 + l0t];
            float4 wv = *(const float4*)&Wout[k*OUTC + c0];
            acc[0][0]=fmaf(yv.x,wv.x,acc[0][0]); acc[0][1]=fmaf(yv.x,wv.y,acc[0][1]);
            acc[0][2]=fmaf(yv.x,wv.z,acc[0][2]); acc[0][3]=fmaf(yv.x,wv.w,acc[0][3]);
            acc[1][0]=fmaf(yv.y,wv.x,acc[1][0]); acc[1][1]=fmaf(yv.y,wv.y,acc[1][1]);
            acc[1][2]=fmaf(yv.y,wv.z,acc[1][2]); acc[1][3]=fmaf(yv.y,wv.w,acc[1][3]);
        }
        float4 gm = *(const float4*)&lng[c0];
        float4 bt = *(const float4*)&lnb[c0];
        #pragma unroll
        for (int i=0;i<2;++i){
            float rs = acc[i][0]+acc[i][1]+acc[i][2]+acc[i][3];
            #pragma unroll
            for (int m=16;m>0;m>>=1) rs += __shfl_xor(rs, m, 64);
            float mu = rs * (1.f/128.f);
            float d0 = acc[i][0]-mu, d1 = acc[i][1]-mu, d2 = acc[i][2]-mu, d3 = acc[i][3]-mu;
            float sq = d0*d0+d1*d1+d2*d2+d3*d3;
            #pragma unroll
            for (int m=16;m>0;m>>=1) sq += __shfl_xor(sq, m, 64);
            float rstd = rsqrtf(sq * (1.f/128.f) + 1e-5f);
            int lidx = l0t + i;
            os[(c0+0)*18 + lidx] = d0*rstd*gm.x + bt.x;
            os[(c0+1)*18 + lidx] = d1*rstd*gm.y + bt.y;
            os[(c0+2)*18 + lidx] = d2*rstd*gm.z + bt.z;
            os[(c0+3)*18 + lidx] = d3*rstd*gm.w + bt.w;
        }
    }
    __syncthreads();
    // store: cc = t>>1 (0..127), sel = t&1 -> 8 consecutive l = 32B per lane
    {
        int cc = t >> 1, sel = t & 1;
        const float* ip = &os[cc*18 + sel*8];
        float2 a0 = *(const float2*)(ip);
        float2 a1 = *(const float2*)(ip+2);
        float2 a2 = *(const float2*)(ip+4);
        float2 a3 = *(const float2*)(ip+6);
        float* op = out + ((size_t)(b*OUTC + cc))*Lseq + l0 + sel*8;
        *(float4*)(op)   = make_float4(a0.x,a0.y,a1.x,a1.y);
        *(float4*)(op+4) = make_float4(a2.x,a2.y,a3.x,a3.y);
    }
}

extern "C" void kernel_launch(void* const* d_in, const int* in_sizes, int n_in,
                              void* d_out, int out_size, void* d_ws, size_t ws_size,
                              hipStream_t stream) {
    const float* x1    = (const float*)d_in[0];
    const float* Win   = (const float*)d_in[1];
    const float* convw = (const float*)d_in[2];
    const float* convb = (const float*)d_in[3];
    const float* Wx    = (const float*)d_in[4];
    const float* Wdt   = (const float*)d_in[5];
    const float* bdt   = (const float*)d_in[6];
    const float* Alog  = (const float*)d_in[7];
    const float* Dv    = (const float*)d_in[8];
    const float* Wout  = (const float*)d_in[9];
    const float* lng   = (const float*)d_in[10];
    const float* lnb   = (const float*)d_in[11];
    float* out = (float*)d_out;

    float2*   PSw = (float2*)d_ws;                 // 2,097,152 float2 = 16 MB
    float*    Iw  = (float*)(PSw + 2097152);       // 2,097,152 float  =  8 MB
    unsigned* bar = (unsigned*)(Iw + 2097152);     // barrier counter (8 B)

    hipMemsetAsync(bar, 0, 8, stream);             // reset barrier each replay
    k_fused<<<512, 256, 0, stream>>>(x1, Win, convw, convb, Wx, Wdt, bdt, Alog,
                                     Dv, Wout, lng, lnb, PSw, Iw, bar, out);
}

// Round 19
// 369.158 us; speedup vs baseline: 1.1019x; 1.0811x over previous
//
#include <hip/hip_runtime.h>
#include <math.h>

#define B_ 2
#define DMODEL 128
#define DIN 256
#define DSTATE 16
#define DTR 8
#define OUTC 128
#define Lseq 4096
#define NC 256          // chunks per batch
#define LC 16           // timesteps per chunk
#define NBLK 512        // grid size (must equal launch grid; 2 blocks/CU, all co-resident)
#define FSTRIDE 16      // flag padding: 16 words = 64B = one cache line per flag

__device__ __forceinline__ float siluf(float x){ return x / (1.f + __expf(-x)); }

// dA[s] = e1^(s+1), s=0..15, via log-depth power ladder (15 muls, depth ~4).
__device__ __forceinline__ void build_dA(float e1, float* dAv){
    float e2 = e1*e1, e4 = e2*e2, e8 = e4*e4;
    dAv[0]=e1;         dAv[1]=e2;         dAv[2]=e2*e1;       dAv[3]=e4;
    dAv[4]=e4*e1;      dAv[5]=e4*e2;      dAv[6]=e4*dAv[2];   dAv[7]=e8;
    dAv[8]=e8*e1;      dAv[9]=e8*e2;      dAv[10]=e8*dAv[2];  dAv[11]=e8*e4;
    dAv[12]=e8*dAv[4]; dAv[13]=e8*dAv[5]; dAv[14]=e8*dAv[6];  dAv[15]=e8*e8;
}

__device__ __forceinline__ float softplusf(float a){
    return (a > 20.f) ? a : __logf(1.f + __expf(a));
}

// Grid barrier v3 — R18 post-mortem: 512 pollers on ONE line saturate the coherence queue
// regardless of load-vs-RMW (R15 & R18: identical 377MB traffic, ~130us/barrier).
// Structural fix: (a) sharded arrival across 8 lines; (b) ONE poller (block 0) collects;
// (c) release via per-block PRIVATE flag lines (64B apart) -> zero inter-block poll contention.
// Fence chain (release-fence -> arrive; observe -> acquire-fence) identical to R15-verified scheme.
// bar layout: [0..127] 8 shard counters (16-word stride); [128..8319] 512 flags (16-word stride).
__device__ __forceinline__ void gridbar(unsigned* bar, unsigned gen, int blk, int t){
    unsigned* shards = bar;
    unsigned* flags  = bar + 8*FSTRIDE;
    __syncthreads();                       // all block stores issued & complete
    if (t == 0){
        __threadfence();                   // release: push this block's writes to coherence point
        atomicAdd(&shards[(blk & 7)*FSTRIDE], 1u);
    }
    if (blk == 0){
        if (t == 0){
            for(;;){
                unsigned s = 0;
                #pragma unroll
                for (int i=0;i<8;++i)
                    s += __hip_atomic_load(&shards[i*FSTRIDE], __ATOMIC_RELAXED, __HIP_MEMORY_SCOPE_AGENT);
                if (s >= gen*NBLK) break;
                __builtin_amdgcn_s_sleep(16);
            }
            __threadfence();
        }
        __syncthreads();                   // master block: all threads see completion
        for (int i = t; i < NBLK; i += 256)
            __hip_atomic_store(&flags[i*FSTRIDE], gen, __ATOMIC_RELAXED, __HIP_MEMORY_SCOPE_AGENT);
    }
    if (t == 0){
        while (__hip_atomic_load(&flags[blk*FSTRIDE], __ATOMIC_RELAXED, __HIP_MEMORY_SCOPE_AGENT) < gen){
            __builtin_amdgcn_s_sleep(16);  // private line: contention-free poll
        }
        __threadfence();                   // acquire: discard stale cached lines
    }
    __syncthreads();                       // rest of block waits for t0
}

// =========================================================================================
// FUSED kernel (plain launch + sharded grid barrier): 512 blocks x 256 threads, 2/CU resident.
//   Phase 1 (block = chunk): in_proj GEMM + conv + x_proj + dt_proj + scan pass 1 -> PSw.
//   gridbar(gen=1)
//   Phase 2 (block = r-group): hierarchical chunk combine PSw -> Iw (entry states).
//   gridbar(gen=2)
//   Phase 3 (same block = same chunk): scan pass 3 from hot LDS/registers + out_proj + LN + store.
// Dataflow + fence scheme correctness VERIFIED in R15/R18 (absmax 4.88e-4).
// __launch_bounds__(256,2): pins VGPR <= 256 so 2 blocks/CU co-residency is GUARANTEED.
// =========================================================================================
__global__ __launch_bounds__(256, 2) void k_fused(const float* __restrict__ x1,
        const float* __restrict__ Win,
        const float* __restrict__ convw, const float* __restrict__ convb,
        const float* __restrict__ Wx, const float* __restrict__ Wdt,
        const float* __restrict__ bdt, const float* __restrict__ Alog,
        const float* __restrict__ Dv, const float* __restrict__ Wout,
        const float* __restrict__ lng, const float* __restrict__ lnb,
        float2* __restrict__ PSw, float* __restrict__ Iw, unsigned* __restrict__ bar,
        float* __restrict__ out){
    __shared__ float sbuf[10240];
    __shared__ float xcs[16*257];      // conv output [l][d] — live phase 1 -> phase 3
    __shared__ float xdbl[16*40];      // x_proj output [l][40] — live phase 1 -> phase 3

    int blk = blockIdx.x;              // 512 = b x 256 chunks
    int b  = blk >> 8;
    int cb = blk & 255;
    int l0 = cb << 4;
    int t  = threadIdx.x;

    // ==================== PHASE 1 ====================
    float* xt  = sbuf;                 // [c][p] stride 20 (80B rows, 16B-aligned)
    float* Wxs = sbuf;
    const float* xb = x1 + (size_t)b * DMODEL * Lseq;
    for (int e = t; e < 128*19; e += 256){
        int c = e / 19, p = e - c*19;
        int l = l0 - 3 + p;
        xt[c*20 + p] = (l >= 0) ? xb[(size_t)c*Lseq + l] : 0.f;
    }
    __syncthreads();

    // ---- in_proj GEMM. thread t -> xin col t (19 p incl halo) + z col t (16 p) ----
    float acc0[19], acc1[16];
    #pragma unroll
    for (int p=0;p<19;++p){acc0[p]=0.f;}
    #pragma unroll
    for (int p=0;p<16;++p){acc1[p]=0.f;}
    #pragma unroll 4
    for (int k=0;k<DMODEL;++k){
        float w0 = Win[k*512 + t];
        float w1 = Win[k*512 + t + 256];
        const float4* xp = (const float4*)&xt[k*20];
        float4 v0 = xp[0], v1 = xp[1], v2 = xp[2], v3 = xp[3], v4 = xp[4];
        float xv[19] = { v0.x,v0.y,v0.z,v0.w, v1.x,v1.y,v1.z,v1.w,
                         v2.x,v2.y,v2.z,v2.w, v3.x,v3.y,v3.z,v3.w,
                         v4.x,v4.y,v4.z };
        #pragma unroll
        for (int p=0;p<19;++p) acc0[p] = fmaf(xv[p], w0, acc0[p]);
        #pragma unroll
        for (int p=0;p<16;++p) acc1[p] = fmaf(xv[p+3], w1, acc1[p]);
    }
    // z gate: keep in REGISTERS
    float zvv[16];
    #pragma unroll
    for (int p=0;p<16;++p) zvv[p] = siluf(acc1[p]);

    // ---- causal depthwise conv + silu from registers -> xcs (LDS only) ----
    {
        float cw0 = convw[t*4+0], cw1 = convw[t*4+1], cw2 = convw[t*4+2], cw3 = convw[t*4+3];
        float bb = convb[t];
        #pragma unroll
        for (int l = 0; l < 16; ++l){
            float acc = bb;
            acc = fmaf(acc0[l],   cw0, acc);
            acc = fmaf(acc0[l+1], cw1, acc);
            acc = fmaf(acc0[l+2], cw2, acc);
            acc = fmaf(acc0[l+3], cw3, acc);
            xcs[l*257 + t] = siluf(acc);
        }
    }
    __syncthreads();                   // all waves done reading xt

    // ---- stage Wx into LDS (coalesced float4) ----
    {
        const float4* Wg = (const float4*)Wx;
        float4* Ws = (float4*)Wxs;
        #pragma unroll
        for (int e = t; e < 2560; e += 256)
            Ws[e] = Wg[e];
    }
    __syncthreads();

    // ---- x_proj from LDS (128 active threads: 16 rows x 8 col-groups of 5) ----
    if (t < 128){
        int jg = t & 7;
        int lg = t >> 3;
        int j0 = jg * 5;
        float a0=0.f, a1=0.f, a2=0.f, a3=0.f, a4=0.f;
        const float* xrow = xcs + lg*257;
        const float* wbase = Wxs + j0;
        #pragma unroll 8
        for (int d = 0; d < 256; ++d){
            float xv = xrow[d];
            const float* wr = wbase + d*40;
            a0 = fmaf(xv, wr[0], a0);
            a1 = fmaf(xv, wr[1], a1);
            a2 = fmaf(xv, wr[2], a2);
            a3 = fmaf(xv, wr[3], a3);
            a4 = fmaf(xv, wr[4], a4);
        }
        float* xo = xdbl + lg*40 + j0;
        xo[0]=a0; xo[1]=a1; xo[2]=a2; xo[3]=a3; xo[4]=a4;
    }
    __syncthreads();

    // ---- dt_proj + softplus + fused scan pass 1; dtv in registers; ONLY PSw stored ----
    float Av[16], dtv[16];
    bool fastA = true;
    {
        float wd[DTR];
        #pragma unroll
        for (int r=0;r<DTR;++r) wd[r] = Wdt[r*DIN + t];
        float bv = bdt[t];
        {
            const float4* Ap = (const float4*)(Alog + t*DSTATE);
            #pragma unroll
            for (int q=0;q<4;++q){
                float4 a = Ap[q];
                Av[q*4]   = -__expf(a.x);
                Av[q*4+1] = -__expf(a.y);
                Av[q*4+2] = -__expf(a.z);
                Av[q*4+3] = -__expf(a.w);
            }
        }
        #pragma unroll
        for (int i=1;i<16;++i)
            fastA = fastA && (fabsf(Av[i] - (float)(i+1)*Av[0]) <= 1e-6f*fabsf(Av[i]));
        float P[16], S[16];
        #pragma unroll
        for (int s=0;s<16;++s){ P[s]=1.f; S[s]=0.f; }
        #pragma unroll
        for (int l=0;l<16;++l){
            float a = bv;
            #pragma unroll
            for (int r=0;r<DTR;++r) a = fmaf(xdbl[l*40 + r], wd[r], a);
            float dtvl = softplusf(a);
            dtv[l] = dtvl;
            float xcv = xcs[l*257 + t];
            float dx  = dtvl*xcv;
            const float4* Bv = (const float4*)&xdbl[l*40 + DTR];
            float4 B0 = Bv[0], B1 = Bv[1], B2 = Bv[2], B3 = Bv[3];
            float dAv[16];
            if (fastA){
                build_dA(__expf(dtvl*Av[0]), dAv);
            } else {
                #pragma unroll
                for (int i=0;i<16;++i) dAv[i] = __expf(dtvl*Av[i]);
            }
            #define ST1(i, bval) { P[i] *= dAv[i]; S[i] = fmaf(dAv[i], S[i], dx*(bval)); }
            ST1(0,B0.x) ST1(1,B0.y) ST1(2,B0.z) ST1(3,B0.w)
            ST1(4,B1.x) ST1(5,B1.y) ST1(6,B1.z) ST1(7,B1.w)
            ST1(8,B2.x) ST1(9,B2.y) ST1(10,B2.z) ST1(11,B2.w)
            ST1(12,B3.x) ST1(13,B3.y) ST1(14,B3.z) ST1(15,B3.w)
            #undef ST1
        }
        // PSw per-chunk layout [s][d]: coalesced 512B stores
        float2* ps2 = PSw + ((size_t)(b*NC + cb))*4096;
        #pragma unroll
        for (int s=0;s<16;++s) ps2[s*256 + t] = make_float2(P[s], S[s]);
    }

    gridbar(bar, 1u, blk, t);   // ============ all PSw globally visible ============

    // ==================== PHASE 2: chunk combine (block = r-group of 16) ====================
    {
        float2* gps = (float2*)sbuf;       // [16][16] float2
        float*  ge  = sbuf + 512;          // [16][16] float
        int r0 = (blk & 255) * 16;
        int rr = t & 15;
        int cg2 = t >> 4;                  // chunk-group 0..15 (16 chunks each)
        size_t base = ((size_t)(b*NC + cg2*16))*4096 + r0 + rr;
        float Pl[16], Sl[16];
        float Pa = 1.f, Sa = 0.f;
        #pragma unroll
        for (int i=0;i<16;++i){
            float2 ps = PSw[base + (size_t)i*4096];
            Pl[i] = ps.x; Sl[i] = ps.y;
            Pa = ps.x * Pa;
            Sa = fmaf(ps.x, Sa, ps.y);
        }
        gps[cg2*16 + rr] = make_float2(Pa, Sa);
        __syncthreads();
        if (t < 16){
            float H = 0.f;
            #pragma unroll
            for (int g=0; g<16; ++g){
                float2 ps = gps[g*16 + t];
                ge[g*16 + t] = H;
                H = fmaf(ps.x, H, ps.y);
            }
        }
        __syncthreads();
        float H = ge[cg2*16 + rr];
        #pragma unroll
        for (int i=0;i<16;++i){
            Iw[base + (size_t)i*4096] = H;
            H = fmaf(Pl[i], H, Sl[i]);
        }
    }

    gridbar(bar, 2u, blk, t);   // ============ all Iw globally visible ============

    // ==================== PHASE 3: scan pass 3 + out_proj + LN + store ====================
    float* ysm = sbuf;          // [256*18]
    float* os  = sbuf + 4608;   // [128*18]
    float h[16];
    {   // entry states: Iw per-chunk layout [s][d] -> 16 coalesced b32 loads
        const float* Ip = Iw + ((size_t)(b*NC + cb))*4096 + t;
        #pragma unroll
        for (int s=0;s<16;++s) h[s] = Ip[s*256];
    }
    float Dd = Dv[t];
    #pragma unroll
    for (int l=0;l<LC;++l){
        float dtl = dtv[l];
        float xcv = xcs[l*257 + t];
        float dx  = dtl*xcv;
        const float4* Bv = (const float4*)&xdbl[l*40 + DTR];
        float4 B0 = Bv[0], B1 = Bv[1], B2 = Bv[2], B3 = Bv[3];
        const float4* Cv = (const float4*)&xdbl[l*40 + DTR + DSTATE];
        float4 C0 = Cv[0], C1 = Cv[1], C2 = Cv[2], C3 = Cv[3];
        float dAv[16];
        if (fastA){
            build_dA(__expf(dtl*Av[0]), dAv);
        } else {
            #pragma unroll
            for (int i=0;i<16;++i) dAv[i] = __expf(dtl*Av[i]);
        }
        float y = 0.f;
        #define ST3(i, bval, cval) { h[i] = fmaf(dAv[i], h[i], dx*(bval)); y = fmaf(h[i], (cval), y); }
        ST3(0,B0.x,C0.x) ST3(1,B0.y,C0.y) ST3(2,B0.z,C0.z) ST3(3,B0.w,C0.w)
        ST3(4,B1.x,C1.x) ST3(5,B1.y,C1.y) ST3(6,B1.z,C1.z) ST3(7,B1.w,C1.w)
        ST3(8,B2.x,C2.x) ST3(9,B2.y,C2.y) ST3(10,B2.z,C2.z) ST3(11,B2.w,C2.w)
        ST3(12,B3.x,C3.x) ST3(13,B3.y,C3.y) ST3(14,B3.z,C3.z) ST3(15,B3.w,C3.w)
        #undef ST3
        ysm[t*18 + l] = (y + Dd*xcv)*zvv[l];
    }
    __syncthreads();
    // ---- out_proj: 16l x 128c tile. lg=t>>5 -> l {lg*2, lg*2+1}; cg=t&31 -> 4 c.
    {
        int lg = t >> 5, cgc = t & 31;
        int l0t = lg*2, c0 = cgc*4;
        float acc[2][4];
        #pragma unroll
        for (int i=0;i<2;++i)
            #pragma unroll
            for (int j=0;j<4;++j) acc[i][j]=0.f;
        #pragma unroll 4
        for (int k=0;k<DIN;++k){
            float2 yv = *(const float2*)&ysm[k*18 + l0t];
            float4 wv = *(const float4*)&Wout[k*OUTC + c0];
            acc[0][0]=fmaf(yv.x,wv.x,acc[0][0]); acc[0][1]=fmaf(yv.x,wv.y,acc[0][1]);
            acc[0][2]=fmaf(yv.x,wv.z,acc[0][2]); acc[0][3]=fmaf(yv.x,wv.w,acc[0][3]);
            acc[1][0]=fmaf(yv.y,wv.x,acc[1][0]); acc[1][1]=fmaf(yv.y,wv.y,acc[1][1]);
            acc[1][2]=fmaf(yv.y,wv.z,acc[1][2]); acc[1][3]=fmaf(yv.y,wv.w,acc[1][3]);
        }
        float4 gm = *(const float4*)&lng[c0];
        float4 bt = *(const float4*)&lnb[c0];
        #pragma unroll
        for (int i=0;i<2;++i){
            float rs = acc[i][0]+acc[i][1]+acc[i][2]+acc[i][3];
            #pragma unroll
            for (int m=16;m>0;m>>=1) rs += __shfl_xor(rs, m, 64);
            float mu = rs * (1.f/128.f);
            float d0 = acc[i][0]-mu, d1 = acc[i][1]-mu, d2 = acc[i][2]-mu, d3 = acc[i][3]-mu;
            float sq = d0*d0+d1*d1+d2*d2+d3*d3;
            #pragma unroll
            for (int m=16;m>0;m>>=1) sq += __shfl_xor(sq, m, 64);
            float rstd = rsqrtf(sq * (1.f/128.f) + 1e-5f);
            int lidx = l0t + i;
            os[(c0+0)*18 + lidx] = d0*rstd*gm.x + bt.x;
            os[(c0+1)*18 + lidx] = d1*rstd*gm.y + bt.y;
            os[(c0+2)*18 + lidx] = d2*rstd*gm.z + bt.z;
            os[(c0+3)*18 + lidx] = d3*rstd*gm.w + bt.w;
        }
    }
    __syncthreads();
    // store: cc = t>>1 (0..127), sel = t&1 -> 8 consecutive l = 32B per lane
    {
        int cc = t >> 1, sel = t & 1;
        const float* ip = &os[cc*18 + sel*8];
        float2 a0 = *(const float2*)(ip);
        float2 a1 = *(const float2*)(ip+2);
        float2 a2 = *(const float2*)(ip+4);
        float2 a3 = *(const float2*)(ip+6);
        float* op = out + ((size_t)(b*OUTC + cc))*Lseq + l0 + sel*8;
        *(float4*)(op)   = make_float4(a0.x,a0.y,a1.x,a1.y);
        *(float4*)(op+4) = make_float4(a2.x,a2.y,a3.x,a3.y);
    }
}

extern "C" void kernel_launch(void* const* d_in, const int* in_sizes, int n_in,
                              void* d_out, int out_size, void* d_ws, size_t ws_size,
                              hipStream_t stream) {
    const float* x1    = (const float*)d_in[0];
    const float* Win   = (const float*)d_in[1];
    const float* convw = (const float*)d_in[2];
    const float* convb = (const float*)d_in[3];
    const float* Wx    = (const float*)d_in[4];
    const float* Wdt   = (const float*)d_in[5];
    const float* bdt   = (const float*)d_in[6];
    const float* Alog  = (const float*)d_in[7];
    const float* Dv    = (const float*)d_in[8];
    const float* Wout  = (const float*)d_in[9];
    const float* lng   = (const float*)d_in[10];
    const float* lnb   = (const float*)d_in[11];
    float* out = (float*)d_out;

    float2*   PSw = (float2*)d_ws;                 // 2,097,152 float2 = 16 MB
    float*    Iw  = (float*)(PSw + 2097152);       // 2,097,152 float  =  8 MB
    unsigned* bar = (unsigned*)(Iw + 2097152);     // 8 shard ctrs + 512 flags, 64B-strided

    hipMemsetAsync(bar, 0, (8 + NBLK) * FSTRIDE * sizeof(unsigned), stream);
    k_fused<<<512, 256, 0, stream>>>(x1, Win, convw, convb, Wx, Wdt, bdt, Alog,
                                     Dv, Wout, lng, lnb, PSw, Iw, bar, out);
}